// Round 1
// baseline (161.045 us; speedup 1.0000x reference)
//
#include <hip/hip_runtime.h>

// LikelihoodRatioEstimator: N=8192, D=128 fp32 inputs, 8 fp32 scalar outputs.
//
// Math: d2[i][j] = ||x_i||^2 + ||y_j||^2 - 2 x_i.y_j  (clamped >= 0)
//   logits = -log1p(d2); exp(logits) = 1/(1+d2)
//   B = log(mean_offdiag(1/(1+d2)))              [log_baseline]
//   mean_neg = -mean_offdiag(log1p(d2)) - B
//   repulsion = mean_offdiag(1/(1+d2)) * exp(-B)  (~1.0)
//   mean_sig_neg = mean_offdiag(1/(1 + c*(1+d2))), c = exp(B)  -> needs 2nd pass
//   pos path uses diagonal only (O(N*D), exact fp32).
//
// Gram matrix via bf16 MFMA (fp32 row norms exact); two compute passes over
// the 8192^2 pairs, per-block float partials -> double reduction.
//
// Workspace layout (~4.3 MB):
//   [0, 2MB)        xb   bf16 x (8192x128)
//   [2MB, 4MB)      yb   bf16 y
//   [4MB ...)       x2[8192], y2[8192], posl[8192] (f32)
//                   parts0[4096], parts1[4096], partsB[4096] (f32)
//                   scal[16] (f32 scalars between kernels)

#define N_ROWS 8192
#define DDIM 128
#define NTILE 64            // 8192 / 128
#define NBLK (NTILE * NTILE)
#define NN1 67100672.0      // 8192 * 8191

typedef __bf16 bf16x8 __attribute__((ext_vector_type(8)));
typedef float f32x4 __attribute__((ext_vector_type(4)));

__device__ __forceinline__ unsigned short f32_to_bf16(float f) {
  unsigned int u = __float_as_uint(f);
  u += 0x7FFFu + ((u >> 16) & 1u);   // RNE
  return (unsigned short)(u >> 16);
}

// ---------------------------------------------------------------------------
// prep: fp32 -> bf16 conversion, row norms (exact fp32), diagonal logits.
// One wave per row; lane l handles elements 2l, 2l+1.
__global__ __launch_bounds__(256) void prep_kernel(
    const float* __restrict__ x, const float* __restrict__ y,
    unsigned short* __restrict__ xb, unsigned short* __restrict__ yb,
    float* __restrict__ x2, float* __restrict__ y2, float* __restrict__ posl) {
  int wave = threadIdx.x >> 6, lane = threadIdx.x & 63;
  int r = blockIdx.x * 4 + wave;
  float2 xv = ((const float2*)(x + (size_t)r * DDIM))[lane];
  float2 yv = ((const float2*)(y + (size_t)r * DDIM))[lane];

  unsigned int px = (unsigned int)f32_to_bf16(xv.x) |
                    ((unsigned int)f32_to_bf16(xv.y) << 16);
  unsigned int py = (unsigned int)f32_to_bf16(yv.x) |
                    ((unsigned int)f32_to_bf16(yv.y) << 16);
  ((unsigned int*)xb)[(size_t)r * (DDIM / 2) + lane] = px;
  ((unsigned int*)yb)[(size_t)r * (DDIM / 2) + lane] = py;

  float xx = fmaf(xv.x, xv.x, xv.y * xv.y);
  float yy = fmaf(yv.x, yv.x, yv.y * yv.y);
  float xy = fmaf(xv.x, yv.x, xv.y * yv.y);
  #pragma unroll
  for (int o = 32; o; o >>= 1) {
    xx += __shfl_xor(xx, o);
    yy += __shfl_xor(yy, o);
    xy += __shfl_xor(xy, o);
  }
  if (lane == 0) {
    x2[r] = xx;
    y2[r] = yy;
    float d2 = fmaxf(xx + yy - 2.0f * xy, 0.0f);
    posl[r] = -__logf(1.0f + d2);
  }
}

// ---------------------------------------------------------------------------
// gram pass: 128x128 tile per block, 4 waves (2x2), 4x4 MFMA 16x16x32 frags
// per wave. XOR-swizzled LDS (chunk ^= row&15) keeps ds_read_b128 at 2-way.
// PASS 0: s0 = sum 1/(1+d2), s1 = sum log1p(d2)   (off-diagonal)
// PASS 1: s0 = sum 1/(1 + c*(1+d2))               (off-diagonal)
template <int PASS>
__global__ __launch_bounds__(256) void gram_kernel(
    const unsigned short* __restrict__ xb, const unsigned short* __restrict__ yb,
    const float* __restrict__ x2, const float* __restrict__ y2,
    const float* __restrict__ scal,
    float* __restrict__ parts0, float* __restrict__ parts1) {
  __shared__ uint4 Asm[2048];   // 128 rows x 16 chunks (16B) = 32 KB
  __shared__ uint4 Bsm[2048];
  __shared__ float x2t[128], y2t[128];
  __shared__ float redbuf[8];

  int tid = threadIdx.x;
  int bid = blockIdx.x;
  int tr = bid >> 6, tc = bid & 63;

  const uint4* Ag = (const uint4*)xb + (size_t)tr * 128 * 16;
  const uint4* Bg = (const uint4*)yb + (size_t)tc * 128 * 16;
  #pragma unroll
  for (int it = 0; it < 8; ++it) {
    int cid = tid + it * 256;
    int row = cid >> 4, c = cid & 15;
    uint4 va = Ag[row * 16 + c];
    uint4 vb = Bg[row * 16 + c];
    int sw = row * 16 + (c ^ (row & 15));
    Asm[sw] = va;
    Bsm[sw] = vb;
  }
  if (tid < 128) x2t[tid] = x2[tr * 128 + tid];
  else           y2t[tid - 128] = y2[tc * 128 + (tid - 128)];

  float cc = 0.0f, cc1 = 0.0f;
  if (PASS == 1) { cc = scal[0]; cc1 = 1.0f + cc; }
  __syncthreads();

  int wave = tid >> 6, lane = tid & 63;
  int wr = wave >> 1, wc = wave & 1;
  int quad = lane >> 4, m = lane & 15;

  f32x4 acc[4][4];
  #pragma unroll
  for (int i = 0; i < 4; ++i)
    #pragma unroll
    for (int j = 0; j < 4; ++j)
      acc[i][j] = (f32x4){0.f, 0.f, 0.f, 0.f};

  const bf16x8* A8 = (const bf16x8*)Asm;
  const bf16x8* B8 = (const bf16x8*)Bsm;
  int arow0 = wr * 64 + m;
  int brow0 = wc * 64 + m;

  #pragma unroll
  for (int ks = 0; ks < 4; ++ks) {
    int ch = (ks * 4 + quad) ^ m;
    bf16x8 af[4], bfr[4];
    #pragma unroll
    for (int f = 0; f < 4; ++f) {
      af[f]  = A8[(arow0 + f * 16) * 16 + ch];
      bfr[f] = B8[(brow0 + f * 16) * 16 + ch];
    }
    #pragma unroll
    for (int fi = 0; fi < 4; ++fi)
      #pragma unroll
      for (int fj = 0; fj < 4; ++fj)
        acc[fi][fj] = __builtin_amdgcn_mfma_f32_16x16x32_bf16(
            af[fi], bfr[fj], acc[fi][fj], 0, 0, 0);
  }

  // Epilogue. C/D layout: col = lane&15, row = quad*4 + reg.
  float x2v[16], y2v[4];
  #pragma unroll
  for (int fi = 0; fi < 4; ++fi)
    #pragma unroll
    for (int r = 0; r < 4; ++r)
      x2v[fi * 4 + r] = x2t[wr * 64 + fi * 16 + quad * 4 + r];
  #pragma unroll
  for (int fj = 0; fj < 4; ++fj) y2v[fj] = y2t[wc * 64 + fj * 16 + m];

  int grow0 = tr * 128 + wr * 64 + quad * 4;
  int gcol0 = tc * 128 + wc * 64 + m;

  float s0 = 0.0f, s1 = 0.0f;
  #pragma unroll
  for (int fi = 0; fi < 4; ++fi) {
    #pragma unroll
    for (int fj = 0; fj < 4; ++fj) {
      #pragma unroll
      for (int r = 0; r < 4; ++r) {
        float dot = acc[fi][fj][r];
        float d2 = fmaxf(fmaf(-2.0f, dot, x2v[fi * 4 + r] + y2v[fj]), 0.0f);
        bool off = (grow0 + fi * 16 + r) != (gcol0 + fj * 16);
        if (PASS == 0) {
          float e = __builtin_amdgcn_rcpf(1.0f + d2);
          float lg = __logf(1.0f + d2);
          s0 += off ? e : 0.0f;
          s1 += off ? lg : 0.0f;
        } else {
          float s = __builtin_amdgcn_rcpf(fmaf(cc, d2, cc1));
          s0 += off ? s : 0.0f;
        }
      }
    }
  }

  #pragma unroll
  for (int o = 32; o; o >>= 1) {
    s0 += __shfl_xor(s0, o);
    if (PASS == 0) s1 += __shfl_xor(s1, o);
  }
  if (lane == 0) {
    redbuf[wave] = s0;
    redbuf[wave + 4] = s1;
  }
  __syncthreads();
  if (tid == 0) {
    parts0[bid] = redbuf[0] + redbuf[1] + redbuf[2] + redbuf[3];
    if (PASS == 0)
      parts1[bid] = redbuf[4] + redbuf[5] + redbuf[6] + redbuf[7];
  }
}

// ---------------------------------------------------------------------------
__device__ __forceinline__ double block_reduce_d(double v, double* buf) {
  int tid = threadIdx.x;
  buf[tid] = v;
  __syncthreads();
  #pragma unroll
  for (int s = 128; s > 0; s >>= 1) {
    if (tid < s) buf[tid] += buf[tid + s];
    __syncthreads();
  }
  double r = buf[0];
  __syncthreads();
  return r;
}

__global__ __launch_bounds__(256) void finA_kernel(
    const float* __restrict__ parts0, const float* __restrict__ parts1,
    const float* __restrict__ posl, float* __restrict__ scal) {
  __shared__ double buf[256];
  __shared__ float sBf;
  int tid = threadIdx.x;
  double se = 0.0, sl = 0.0;
  for (int i = tid; i < NBLK; i += 256) {
    se += (double)parts0[i];
    sl += (double)parts1[i];
  }
  double s_exp = block_reduce_d(se, buf);
  double s_lg  = block_reduce_d(sl, buf);
  if (tid == 0) {
    double me = s_exp / NN1;
    sBf = (float)log(me);
  }
  __syncthreads();
  float Bf = sBf;
  double sp = 0.0, ss = 0.0;
  for (int i = tid; i < N_ROWS; i += 256) {
    float p = posl[i];
    sp += (double)p;
    float z = p - Bf;
    ss += (double)(1.0f / (1.0f + __expf(-z)));
  }
  double sum_pos = block_reduce_d(sp, buf);
  double sum_sig = block_reduce_d(ss, buf);
  if (tid == 0) {
    double me = s_exp / NN1;
    double B = log(me);
    double mean_pos = sum_pos / (double)N_ROWS - B;
    scal[0] = (float)me;                       // c = exp(B), for pass B
    scal[1] = (float)B;                        // log_baseline
    scal[2] = (float)mean_pos;                 // mean(pos)
    scal[3] = (float)(-(s_lg) / NN1 - B);      // mean(neg)
    scal[4] = (float)(sum_sig / (double)N_ROWS); // mean(sigmoid(pos))
    scal[5] = (float)(-mean_pos);              // attraction
    scal[6] = (float)(me * exp(-B));           // repulsion (~1.0)
  }
}

__global__ __launch_bounds__(256) void finB_kernel(
    const float* __restrict__ partsB, const float* __restrict__ scal,
    float* __restrict__ out) {
  __shared__ double buf[256];
  int tid = threadIdx.x;
  double sv = 0.0;
  for (int i = tid; i < NBLK; i += 256) sv += (double)partsB[i];
  double s_sig = block_reduce_d(sv, buf);
  if (tid == 0) {
    float att = scal[5], rep = scal[6];
    out[0] = att + rep;              // loss
    out[1] = scal[2];                // mean(pos)
    out[2] = scal[3];                // mean(neg)
    out[3] = scal[4];                // mean(sigmoid(pos))
    out[4] = (float)(s_sig / NN1);   // mean(sigmoid(neg))
    out[5] = att;                    // attraction
    out[6] = rep;                    // repulsion
    out[7] = scal[1];                // log_baseline
  }
}

// ---------------------------------------------------------------------------
extern "C" void kernel_launch(void* const* d_in, const int* in_sizes, int n_in,
                              void* d_out, int out_size, void* d_ws, size_t ws_size,
                              hipStream_t stream) {
  const float* x = (const float*)d_in[0];  // context_embedding
  const float* y = (const float*)d_in[1];  // target_embedding

  char* ws = (char*)d_ws;
  unsigned short* xb = (unsigned short*)ws;
  unsigned short* yb = (unsigned short*)(ws + (size_t)2 * 1024 * 1024);
  float* x2     = (float*)(ws + (size_t)4 * 1024 * 1024);
  float* y2     = x2 + N_ROWS;
  float* posl   = y2 + N_ROWS;
  float* parts0 = posl + N_ROWS;
  float* parts1 = parts0 + NBLK;
  float* partsB = parts1 + NBLK;
  float* scal   = partsB + NBLK;

  hipLaunchKernelGGL(prep_kernel, dim3(2048), dim3(256), 0, stream,
                     x, y, xb, yb, x2, y2, posl);
  hipLaunchKernelGGL(HIP_KERNEL_NAME(gram_kernel<0>), dim3(NBLK), dim3(256), 0,
                     stream, xb, yb, x2, y2, scal, parts0, parts1);
  hipLaunchKernelGGL(finA_kernel, dim3(1), dim3(256), 0, stream,
                     parts0, parts1, posl, scal);
  hipLaunchKernelGGL(HIP_KERNEL_NAME(gram_kernel<1>), dim3(NBLK), dim3(256), 0,
                     stream, xb, yb, x2, y2, scal, partsB, parts1);
  hipLaunchKernelGGL(finB_kernel, dim3(1), dim3(256), 0, stream,
                     partsB, scal, (float*)d_out);
}